// Round 1
// baseline (484.327 us; speedup 1.0000x reference)
//
#include <hip/hip_runtime.h>
#include <math.h>

#define BB 16
#define C1 64
#define C2 64
#define HH 160
#define WW 160
#define KK 4
#define HID 16
#define EPS 1e-5f
#define HWSZ (HH*WW)          // 25600
#define NPB (BB*HWSZ)         // 409600 per-channel element count

// ws layout (float offsets)
#define WS_CTX   0            // 1024
#define WS_AF    1024         // 1024
#define WS_AC    2048         // 1024
#define WS_AS    3072         // 144
#define WS_AW    3216         // 64
#define WS_BIAS  3280         // 1024
#define WS_SC    4304         // 64
#define WS_SH    4368         // 64
#define WS_STATS 4432         // NSLOT*128 = 4096
#define NSLOT    32
#define WS_WEFF  8704         // 16*36864 = 589824

// ---------------- Kernel 1: global average pool ----------------
__global__ void pool_kernel(const float* __restrict__ x, float* __restrict__ ws) {
    int bc = blockIdx.x;  // b*64 + c1, 0..1023
    const float4* p4 = (const float4*)(x + (size_t)bc * HWSZ);
    float s = 0.f;
    for (int i = threadIdx.x; i < HWSZ / 4; i += 256) {
        float4 v = p4[i];
        s += v.x + v.y + v.z + v.w;
    }
    #pragma unroll
    for (int o = 32; o > 0; o >>= 1) s += __shfl_down(s, o, 64);
    __shared__ float ls[4];
    if ((threadIdx.x & 63) == 0) ls[threadIdx.x >> 6] = s;
    __syncthreads();
    if (threadIdx.x == 0)
        ws[WS_CTX + bc] = (ls[0] + ls[1] + ls[2] + ls[3]) * (1.0f / (float)HWSZ);
}

// ---------------- Kernel 2: attention MLP (single block) ----------------
__global__ void attn_kernel(float* __restrict__ ws,
    const float* __restrict__ Wfc, const float* __restrict__ gh, const float* __restrict__ bh,
    const float* __restrict__ Wf,  const float* __restrict__ bf,
    const float* __restrict__ Wsm, const float* __restrict__ bs,
    const float* __restrict__ Wc,  const float* __restrict__ bc,
    const float* __restrict__ Ww,  const float* __restrict__ bw,
    const float* __restrict__ bk) {
    __shared__ float hs[16][16];
    __shared__ float aw[16][4];
    int t = threadIdx.x;

    // h = ctx @ Wfc^T   (16x16, one element per thread)
    {
        int b = t >> 4, j = t & 15;
        const float* cx = ws + WS_CTX + b * 64;
        const float* wr = Wfc + j * 64;
        float s = 0.f;
        #pragma unroll
        for (int c = 0; c < 64; c++) s += cx[c] * wr[c];
        hs[b][j] = s;
    }
    __syncthreads();
    // BatchNorm over batch (biased var) + ReLU
    if (t < 16) {
        int j = t;
        float mu = 0.f;
        #pragma unroll
        for (int b = 0; b < 16; b++) mu += hs[b][j];
        mu *= (1.f / 16.f);
        float vr = 0.f;
        #pragma unroll
        for (int b = 0; b < 16; b++) { float d = hs[b][j] - mu; vr += d * d; }
        vr *= (1.f / 16.f);
        float sc = gh[j] * rsqrtf(vr + EPS);
        float sh = bh[j] - mu * sc;
        #pragma unroll
        for (int b = 0; b < 16; b++) {
            float v = hs[b][j] * sc + sh;
            hs[b][j] = v > 0.f ? v : 0.f;
        }
    }
    __syncthreads();
    // attn_w = softmax(h @ Ww^T + bw) over K=4
    if (t < 16) {
        int b = t;
        float l[4]; float mx = -1e30f;
        #pragma unroll
        for (int k = 0; k < 4; k++) {
            float s = bw[k];
            #pragma unroll
            for (int j = 0; j < 16; j++) s += hs[b][j] * Ww[k * 16 + j];
            l[k] = s; mx = fmaxf(mx, s);
        }
        float den = 0.f;
        #pragma unroll
        for (int k = 0; k < 4; k++) { l[k] = expf(l[k] - mx); den += l[k]; }
        float r = 1.f / den;
        #pragma unroll
        for (int k = 0; k < 4; k++) { float v = l[k] * r; aw[b][k] = v; ws[WS_AW + b * 4 + k] = v; }
    }
    // attn_f, attn_c (1024 each, 4 per thread)
    #pragma unroll
    for (int q = 0; q < 4; q++) {
        int idx = t * 4 + q;
        int b = idx >> 6, c2 = idx & 63;
        float sf = bf[c2], sc2 = bc[c2];
        #pragma unroll
        for (int j = 0; j < 16; j++) {
            float hv = hs[b][j];
            sf  += hv * Wf[c2 * 16 + j];
            sc2 += hv * Wc[c2 * 16 + j];
        }
        ws[WS_AF + idx] = 1.f / (1.f + expf(-sf));
        ws[WS_AC + idx] = 1.f / (1.f + expf(-sc2));
    }
    // attn_s (144)
    if (t < 144) {
        int b = t / 9, uv = t % 9;
        float s = bs[uv];
        #pragma unroll
        for (int j = 0; j < 16; j++) s += hs[b][j] * Wsm[uv * 16 + j];
        ws[WS_AS + t] = 1.f / (1.f + expf(-s));
    }
    __syncthreads();
    // bias = attn_w @ bk  (B x C2)
    #pragma unroll
    for (int q = 0; q < 4; q++) {
        int idx = t * 4 + q;
        int b = idx >> 6, c2 = idx & 63;
        float s = 0.f;
        #pragma unroll
        for (int k = 0; k < 4; k++) s += aw[b][k] * bk[k * 64 + c2];
        ws[WS_BIAS + idx] = s;
    }
    // zero the BN-stat slots
    for (int i = t; i < NSLOT * 128; i += 256) ws[WS_STATS + i] = 0.f;
}

// ---------------- Kernel 3: per-sample effective weights ----------------
// Weff[b][c1][uv][c2] = attn_f[b,c2]*attn_c[b,c1]*attn_s[b,uv]*sum_k aw[b,k]*Wk[k,c2,c1,uv]
__global__ void wprep_kernel(const float* __restrict__ Wk, float* __restrict__ ws) {
    int b = blockIdx.y;
    int e = blockIdx.x * 256 + threadIdx.x;   // < 36864
    int c2 = e & 63;
    int r  = e >> 6;      // c1*9+uv
    int uv = r % 9;
    int c1 = r / 9;
    const float* awp = ws + WS_AW + b * 4;
    float s = 0.f;
    #pragma unroll
    for (int k = 0; k < 4; k++)
        s += awp[k] * Wk[((size_t)(k * 64 + c2) * 64 + c1) * 9 + uv];
    float w = s * ws[WS_AF + b * 64 + c2] * ws[WS_AC + b * 64 + c1] * ws[WS_AS + b * 9 + uv];
    ws[WS_WEFF + (size_t)b * 36864 + e] = w;
}

// ---------------- Kernel 4: per-sample 3x3 conv + fused BN partial stats ----------------
// block: 1 sample, 32x4 spatial tile, all 64 c2. 256 threads: c2g = t&15 (4 c2 each),
// pixg = t>>4 (row = pixg>>2, colb = (pixg&3)*8, 8 px each)
__launch_bounds__(256)
__global__ void conv_kernel(const float* __restrict__ x, float* __restrict__ ws,
                            float* __restrict__ out) {
    __shared__ float xs[16][6][34];     // c1 chunk, halo'd rows/cols
    __shared__ float wsh[16][9][64];    // [c1][uv][c2]
    __shared__ float ssum[64], ssq[64];

    int b = blockIdx.y;
    int tile = blockIdx.x;              // 0..199
    int tileX = (tile % 5) * 32;
    int tileY = (tile / 5) * 4;
    int t = threadIdx.x;
    int c2g  = t & 15;
    int pixg = t >> 4;
    int row  = pixg >> 2;
    int colb = (pixg & 3) << 3;

    if (t < 64) { ssum[t] = 0.f; ssq[t] = 0.f; }

    float acc[4][8];
    #pragma unroll
    for (int i = 0; i < 4; i++) {
        float bv = ws[WS_BIAS + b * 64 + c2g * 4 + i];
        #pragma unroll
        for (int p = 0; p < 8; p++) acc[i][p] = bv;
    }

    const float* xb = x + (size_t)b * C1 * HWSZ;
    const float* weffb = ws + WS_WEFF + (size_t)b * 36864;

    for (int cc = 0; cc < 4; cc++) {
        __syncthreads();
        // stage x tile (16 c1 x 6 x 34 = 3264 floats), zero-padded halo
        for (int i = t; i < 3264; i += 256) {
            int c1i = i / 204;
            int rem = i - c1i * 204;
            int r = rem / 34;
            int c = rem - r * 34;
            int gy = tileY + r - 1;
            int gx = tileX + c - 1;
            float v = 0.f;
            if (gy >= 0 && gy < HH && gx >= 0 && gx < WW)
                v = xb[(size_t)(cc * 16 + c1i) * HWSZ + gy * WW + gx];
            xs[c1i][r][c] = v;
        }
        // stage weights (9216 floats = 2304 float4), coalesced
        {
            const float4* wp = (const float4*)(weffb + cc * 9216);
            float4* wd = (float4*)&wsh[0][0][0];
            for (int i = t; i < 2304; i += 256) wd[i] = wp[i];
        }
        __syncthreads();

        #pragma unroll 2
        for (int c1i = 0; c1i < 16; c1i++) {
            #pragma unroll
            for (int u = 0; u < 3; u++) {
                float xr[10];
                #pragma unroll
                for (int c = 0; c < 10; c++) xr[c] = xs[c1i][row + u][colb + c];
                #pragma unroll
                for (int v = 0; v < 3; v++) {
                    float4 wv = *(const float4*)&wsh[c1i][u * 3 + v][c2g * 4];
                    #pragma unroll
                    for (int p = 0; p < 8; p++) {
                        float xv = xr[v + p];
                        acc[0][p] = fmaf(wv.x, xv, acc[0][p]);
                        acc[1][p] = fmaf(wv.y, xv, acc[1][p]);
                        acc[2][p] = fmaf(wv.z, xv, acc[2][p]);
                        acc[3][p] = fmaf(wv.w, xv, acc[3][p]);
                    }
                }
            }
        }
    }

    // store conv output (+bias already included) and accumulate BN partials
    size_t outbase = (size_t)b * C2 * HWSZ;
    #pragma unroll
    for (int i = 0; i < 4; i++) {
        int c2 = c2g * 4 + i;
        float s = 0.f, q = 0.f;
        #pragma unroll
        for (int p = 0; p < 8; p++) { float v = acc[i][p]; s += v; q += v * v; }
        atomicAdd(&ssum[c2], s);
        atomicAdd(&ssq[c2], q);
        float* op = out + outbase + (size_t)c2 * HWSZ + (size_t)(tileY + row) * WW + tileX + colb;
        ((float4*)op)[0] = make_float4(acc[i][0], acc[i][1], acc[i][2], acc[i][3]);
        ((float4*)op)[1] = make_float4(acc[i][4], acc[i][5], acc[i][6], acc[i][7]);
    }
    __syncthreads();
    if (t < 64) {
        int slot = (blockIdx.y * 200 + blockIdx.x) & (NSLOT - 1);
        float* st = ws + WS_STATS + slot * 128;
        atomicAdd(&st[t], ssum[t]);
        atomicAdd(&st[64 + t], ssq[t]);
    }
}

// ---------------- Kernel 5: finalize BN stats ----------------
__global__ void bnstat_kernel(float* __restrict__ ws, const float* __restrict__ go,
                              const float* __restrict__ bo) {
    int c = threadIdx.x;  // 64
    float s = 0.f, q = 0.f;
    for (int sl = 0; sl < NSLOT; sl++) {
        s += ws[WS_STATS + sl * 128 + c];
        q += ws[WS_STATS + sl * 128 + 64 + c];
    }
    float mu  = s * (1.0f / (float)NPB);
    float var = q * (1.0f / (float)NPB) - mu * mu;
    float sc  = go[c] * rsqrtf(var + EPS);
    ws[WS_SC + c] = sc;
    ws[WS_SH + c] = bo[c] - mu * sc;
}

// ---------------- Kernel 6: in-place BN apply + SiLU ----------------
__global__ void bnact_kernel(float* __restrict__ out, const float* __restrict__ ws) {
    __shared__ float sc[64], sh[64];
    if (threadIdx.x < 64) {
        sc[threadIdx.x] = ws[WS_SC + threadIdx.x];
        sh[threadIdx.x] = ws[WS_SH + threadIdx.x];
    }
    __syncthreads();
    const int n4 = BB * C2 * HWSZ / 4;  // 6,553,600
    for (int i = blockIdx.x * blockDim.x + threadIdx.x; i < n4; i += gridDim.x * blockDim.x) {
        float4 v = ((float4*)out)[i];
        int c = ((i * 4) / HWSZ) & 63;
        float s = sc[c], h = sh[c];
        v.x = v.x * s + h; v.y = v.y * s + h; v.z = v.z * s + h; v.w = v.w * s + h;
        v.x = v.x / (1.f + __expf(-v.x));
        v.y = v.y / (1.f + __expf(-v.y));
        v.z = v.z / (1.f + __expf(-v.z));
        v.w = v.w / (1.f + __expf(-v.w));
        ((float4*)out)[i] = v;
    }
}

extern "C" void kernel_launch(void* const* d_in, const int* in_sizes, int n_in,
                              void* d_out, int out_size, void* d_ws, size_t ws_size,
                              hipStream_t stream) {
    const float* x   = (const float*)d_in[0];
    const float* Wk  = (const float*)d_in[1];
    const float* bk  = (const float*)d_in[2];
    const float* Wfc = (const float*)d_in[3];
    const float* gh  = (const float*)d_in[4];
    const float* bh  = (const float*)d_in[5];
    const float* Wf  = (const float*)d_in[6];
    const float* bf  = (const float*)d_in[7];
    const float* Wsm = (const float*)d_in[8];
    const float* bs  = (const float*)d_in[9];
    const float* Wc  = (const float*)d_in[10];
    const float* bc  = (const float*)d_in[11];
    const float* Ww  = (const float*)d_in[12];
    const float* bw  = (const float*)d_in[13];
    const float* go  = (const float*)d_in[14];
    const float* bo  = (const float*)d_in[15];
    float* out = (float*)d_out;
    float* ws  = (float*)d_ws;

    pool_kernel<<<dim3(1024), dim3(256), 0, stream>>>(x, ws);
    attn_kernel<<<dim3(1), dim3(256), 0, stream>>>(ws, Wfc, gh, bh, Wf, bf, Wsm, bs, Wc, bc, Ww, bw, bk);
    wprep_kernel<<<dim3(144, 16), dim3(256), 0, stream>>>(Wk, ws);
    conv_kernel<<<dim3(200, 16), dim3(256), 0, stream>>>(x, ws, out);
    bnstat_kernel<<<dim3(1), dim3(64), 0, stream>>>(ws, go, bo);
    bnact_kernel<<<dim3(2048), dim3(256), 0, stream>>>(out, ws);
}

// Round 2
// 165.287 us; speedup vs baseline: 2.9302x; 2.9302x over previous
//
#include <hip/hip_runtime.h>
#include <math.h>

#define BB 16
#define C1 64
#define C2 64
#define HH 160
#define WW 160
#define KK 4
#define HID 16
#define EPS 1e-5f
#define HWSZ (HH*WW)          // 25600
#define NPB (BB*HWSZ)         // 409600 per-channel element count

// ws layout (float offsets)
#define WS_CTX   0            // 1024
#define WS_AF    1024         // 1024
#define WS_AC    2048         // 1024
#define WS_AS    3072         // 144
#define WS_AW    3216         // 64
#define WS_BIAS  3280         // 1024
#define WS_SC    4304         // 64
#define WS_SH    4368         // 64
#define WS_STATS 4432         // NSLOT*128 = 4096
#define NSLOT    32
#define WS_WEFF  8704         // bf16 image: 16 * 4608 uint4 = 1.18 MB

typedef __attribute__((ext_vector_type(8)))  short bf16x8;
typedef __attribute__((ext_vector_type(16))) float f32x16;
typedef __attribute__((ext_vector_type(4)))  float f32x4;

__device__ __forceinline__ unsigned short f2bf(float f) {
    unsigned int u = __float_as_uint(f);
    unsigned int r = (u + 0x7FFFu + ((u >> 16) & 1u)) >> 16;
    return (unsigned short)r;
}

// ---------------- Kernel 1: global average pool ----------------
__global__ void pool_kernel(const float* __restrict__ x, float* __restrict__ ws) {
    int bc = blockIdx.x;  // b*64 + c1, 0..1023
    const float4* p4 = (const float4*)(x + (size_t)bc * HWSZ);
    float s = 0.f;
    for (int i = threadIdx.x; i < HWSZ / 4; i += 256) {
        float4 v = p4[i];
        s += v.x + v.y + v.z + v.w;
    }
    #pragma unroll
    for (int o = 32; o > 0; o >>= 1) s += __shfl_down(s, o, 64);
    __shared__ float ls[4];
    if ((threadIdx.x & 63) == 0) ls[threadIdx.x >> 6] = s;
    __syncthreads();
    if (threadIdx.x == 0)
        ws[WS_CTX + bc] = (ls[0] + ls[1] + ls[2] + ls[3]) * (1.0f / (float)HWSZ);
}

// ---------------- Kernel 2: attention MLP (single block) ----------------
__global__ void attn_kernel(float* __restrict__ ws,
    const float* __restrict__ Wfc, const float* __restrict__ gh, const float* __restrict__ bh,
    const float* __restrict__ Wf,  const float* __restrict__ bf,
    const float* __restrict__ Wsm, const float* __restrict__ bs,
    const float* __restrict__ Wc,  const float* __restrict__ bc,
    const float* __restrict__ Ww,  const float* __restrict__ bw,
    const float* __restrict__ bk) {
    __shared__ float hs[16][16];
    __shared__ float aw[16][4];
    int t = threadIdx.x;

    {
        int b = t >> 4, j = t & 15;
        const float* cx = ws + WS_CTX + b * 64;
        const float* wr = Wfc + j * 64;
        float s = 0.f;
        #pragma unroll
        for (int c = 0; c < 64; c++) s += cx[c] * wr[c];
        hs[b][j] = s;
    }
    __syncthreads();
    if (t < 16) {
        int j = t;
        float mu = 0.f;
        #pragma unroll
        for (int b = 0; b < 16; b++) mu += hs[b][j];
        mu *= (1.f / 16.f);
        float vr = 0.f;
        #pragma unroll
        for (int b = 0; b < 16; b++) { float d = hs[b][j] - mu; vr += d * d; }
        vr *= (1.f / 16.f);
        float sc = gh[j] * rsqrtf(vr + EPS);
        float sh = bh[j] - mu * sc;
        #pragma unroll
        for (int b = 0; b < 16; b++) {
            float v = hs[b][j] * sc + sh;
            hs[b][j] = v > 0.f ? v : 0.f;
        }
    }
    __syncthreads();
    if (t < 16) {
        int b = t;
        float l[4]; float mx = -1e30f;
        #pragma unroll
        for (int k = 0; k < 4; k++) {
            float s = bw[k];
            #pragma unroll
            for (int j = 0; j < 16; j++) s += hs[b][j] * Ww[k * 16 + j];
            l[k] = s; mx = fmaxf(mx, s);
        }
        float den = 0.f;
        #pragma unroll
        for (int k = 0; k < 4; k++) { l[k] = expf(l[k] - mx); den += l[k]; }
        float r = 1.f / den;
        #pragma unroll
        for (int k = 0; k < 4; k++) { float v = l[k] * r; aw[b][k] = v; ws[WS_AW + b * 4 + k] = v; }
    }
    #pragma unroll
    for (int q = 0; q < 4; q++) {
        int idx = t * 4 + q;
        int b = idx >> 6, c2 = idx & 63;
        float sf = bf[c2], sc2 = bc[c2];
        #pragma unroll
        for (int j = 0; j < 16; j++) {
            float hv = hs[b][j];
            sf  += hv * Wf[c2 * 16 + j];
            sc2 += hv * Wc[c2 * 16 + j];
        }
        ws[WS_AF + idx] = 1.f / (1.f + expf(-sf));
        ws[WS_AC + idx] = 1.f / (1.f + expf(-sc2));
    }
    if (t < 144) {
        int b = t / 9, uv = t % 9;
        float s = bs[uv];
        #pragma unroll
        for (int j = 0; j < 16; j++) s += hs[b][j] * Wsm[uv * 16 + j];
        ws[WS_AS + t] = 1.f / (1.f + expf(-s));
    }
    __syncthreads();
    #pragma unroll
    for (int q = 0; q < 4; q++) {
        int idx = t * 4 + q;
        int b = idx >> 6, c2 = idx & 63;
        float s = 0.f;
        #pragma unroll
        for (int k = 0; k < 4; k++) s += aw[b][k] * bk[k * 64 + c2];
        ws[WS_BIAS + idx] = s;
    }
    for (int i = t; i < NSLOT * 128; i += 256) ws[WS_STATS + i] = 0.f;
}

// ---------------- Kernel 3: effective weights -> bf16 LDS image ----------------
// unit (chunk, uv, c2, h'): 8 bf16 for c1 = chunk*16 + h*8 .. +7,
// h' = h ^ ((c2>>2)&1)  (pre-swizzled for conflict-free A-frag ds_read_b128)
__global__ void wprep_kernel(const float* __restrict__ Wk, float* __restrict__ ws) {
    int b = blockIdx.y;
    int tid = blockIdx.x * 256 + threadIdx.x;   // < 4608
    int h = tid & 1;
    int c2 = (tid >> 1) & 63;
    int g = tid >> 7;          // 0..35
    int uv = g % 9;
    int chunk = g / 9;
    const float* awp = ws + WS_AW + b * 4;
    float aw0 = awp[0], aw1 = awp[1], aw2 = awp[2], aw3 = awp[3];
    float af = ws[WS_AF + b * 64 + c2];
    float as_ = ws[WS_AS + b * 9 + uv];
    union { uint4 q; unsigned short u[8]; } pk;
    #pragma unroll
    for (int j = 0; j < 8; ++j) {
        int c1 = chunk * 16 + h * 8 + j;
        const float* wp = Wk + (size_t)(c2 * 64 + c1) * 9 + uv;
        float s = aw0 * wp[0] + aw1 * wp[64 * 64 * 9] + aw2 * wp[2 * 64 * 64 * 9] + aw3 * wp[3 * 64 * 64 * 9];
        float w = s * af * ws[WS_AC + b * 64 + c1] * as_;
        pk.u[j] = f2bf(w);
    }
    int unit = ((chunk * 9 + uv) * 64 + c2) * 2 + (h ^ ((c2 >> 2) & 1));
    ((uint4*)(ws + WS_WEFF))[(size_t)b * 4608 + unit] = pk.q;
}

// ---------------- Kernel 4: MFMA implicit-GEMM conv + fused BN partial stats ----------------
// block: 1 sample, 4 rows x 160 cols, all 64 c2. 512 threads = 8 waves.
// wave w: c2blk = w&1 (32 c2), row = w>>1; 5 accs of 32x32 (32 c2 x 32 px).
__launch_bounds__(512)
__global__ void conv_kernel(const float* __restrict__ x, float* __restrict__ ws,
                            float* __restrict__ out) {
    __shared__ unsigned short xs[6 * 162 * 16];   // [row][col][16 c1], 16B-half swizzled by col
    __shared__ unsigned short wsh[9 * 64 * 16];   // [uv][c2][16 c1], swizzled by c2
    __shared__ float bsh[64];

    int b = blockIdx.y;
    int y0 = blockIdx.x * 4;
    int t = threadIdx.x;
    int wv = t >> 6;
    int lane = t & 63;
    int l31 = lane & 31;
    int l5 = lane >> 5;
    int c2blk = wv & 1;
    int rw = wv >> 1;

    if (t < 64) bsh[t] = ws[WS_BIAS + b * 64 + t];

    f32x16 acc[5];
    #pragma unroll
    for (int j = 0; j < 5; ++j)
        #pragma unroll
        for (int r = 0; r < 16; ++r) acc[j][r] = 0.f;

    const float* xb = x + (size_t)b * C1 * HWSZ;
    const uint4* wg = (const uint4*)(ws + WS_WEFF) + (size_t)b * 4608;

    for (int cc = 0; cc < 4; ++cc) {
        __syncthreads();
        // stage weights: 1152 uint4 (already in swizzled LDS-image layout)
        {
            uint4* wd = (uint4*)wsh;
            for (int i = t; i < 1152; i += 512) wd[i] = wg[cc * 1152 + i];
        }
        // stage x: 1944 units of (h, row, col) -> 8 c1 bf16 each
        for (int i = t; i < 1944; i += 512) {
            int col = i % 162;
            int rem = i / 162;
            int row = rem % 6;
            int h = rem / 6;
            int gy = y0 + row - 1;
            int gx = col - 1;
            bool inb = (gy >= 0 && gy < HH && gx >= 0 && gx < WW);
            const float* src = xb + (size_t)(cc * 16 + h * 8) * HWSZ + gy * WW + gx;
            union { uint4 q; unsigned short u[8]; } pk;
            #pragma unroll
            for (int j = 0; j < 8; ++j) {
                float v = inb ? src[j * HWSZ] : 0.f;
                pk.u[j] = f2bf(v);
            }
            int unit = (row * 162 + col) * 2 + (h ^ ((col >> 2) & 1));
            *(uint4*)&xs[unit * 8] = pk.q;
        }
        __syncthreads();

        // compute: 9 taps x 5 pixel-blocks
        #pragma unroll
        for (int uv = 0; uv < 9; ++uv) {
            int u = uv / 3, v = uv % 3;
            int c2 = c2blk * 32 + l31;
            int aunit = (uv * 64 + c2) * 2 + (l5 ^ ((l31 >> 2) & 1));
            bf16x8 a = *(bf16x8*)&wsh[aunit * 8];
            int xrow = rw + u;
            #pragma unroll
            for (int j = 0; j < 5; ++j) {
                int col = j * 32 + l31 + v;
                int bunit = (xrow * 162 + col) * 2 + (l5 ^ ((col >> 2) & 1));
                bf16x8 bb = *(bf16x8*)&xs[bunit * 8];
                acc[j] = __builtin_amdgcn_mfma_f32_32x32x16_bf16(a, bb, acc[j], 0, 0, 0);
            }
        }
    }

    // ---- epilogue: add bias, store, BN partial stats ----
    float bv[16];
    int cb = c2blk * 32 + 4 * l5;
    #pragma unroll
    for (int qq = 0; qq < 4; ++qq) {
        f32x4 bq = *(f32x4*)&bsh[cb + 8 * qq];
        bv[4 * qq + 0] = bq.x; bv[4 * qq + 1] = bq.y;
        bv[4 * qq + 2] = bq.z; bv[4 * qq + 3] = bq.w;
    }

    float* outb = out + (size_t)b * C2 * HWSZ + (size_t)(y0 + rw) * WW;
    float sr[16], qr[16];
    #pragma unroll
    for (int r = 0; r < 16; ++r) { sr[r] = 0.f; qr[r] = 0.f; }
    #pragma unroll
    for (int j = 0; j < 5; ++j) {
        #pragma unroll
        for (int r = 0; r < 16; ++r) {
            int c2 = cb + (r & 3) + 8 * (r >> 2);
            float v = acc[j][r] + bv[r];
            outb[(size_t)c2 * HWSZ + j * 32 + l31] = v;
            sr[r] += v;
            qr[r] = fmaf(v, v, qr[r]);
        }
    }
    // reduce across the 32 lanes sharing each c2 (within 32-lane halves)
    float* st = ws + WS_STATS + (size_t)((b * 40 + blockIdx.x) & (NSLOT - 1)) * 128;
    #pragma unroll
    for (int r = 0; r < 16; ++r) {
        float sv = sr[r], qv = qr[r];
        #pragma unroll
        for (int m = 1; m <= 16; m <<= 1) {
            sv += __shfl_xor(sv, m, 64);
            qv += __shfl_xor(qv, m, 64);
        }
        if (l31 == 0) {
            int c2 = cb + (r & 3) + 8 * (r >> 2);
            atomicAdd(&st[c2], sv);
            atomicAdd(&st[64 + c2], qv);
        }
    }
}

// ---------------- Kernel 5: finalize BN stats ----------------
__global__ void bnstat_kernel(float* __restrict__ ws, const float* __restrict__ go,
                              const float* __restrict__ bo) {
    int c = threadIdx.x;  // 64
    float s = 0.f, q = 0.f;
    for (int sl = 0; sl < NSLOT; sl++) {
        s += ws[WS_STATS + sl * 128 + c];
        q += ws[WS_STATS + sl * 128 + 64 + c];
    }
    float mu  = s * (1.0f / (float)NPB);
    float var = q * (1.0f / (float)NPB) - mu * mu;
    float sc  = go[c] * rsqrtf(var + EPS);
    ws[WS_SC + c] = sc;
    ws[WS_SH + c] = bo[c] - mu * sc;
}

// ---------------- Kernel 6: in-place BN apply + SiLU ----------------
__global__ void bnact_kernel(float* __restrict__ out, const float* __restrict__ ws) {
    __shared__ float sc[64], sh[64];
    if (threadIdx.x < 64) {
        sc[threadIdx.x] = ws[WS_SC + threadIdx.x];
        sh[threadIdx.x] = ws[WS_SH + threadIdx.x];
    }
    __syncthreads();
    const int n4 = BB * C2 * HWSZ / 4;
    for (int i = blockIdx.x * blockDim.x + threadIdx.x; i < n4; i += gridDim.x * blockDim.x) {
        float4 v = ((float4*)out)[i];
        int c = ((i * 4) / HWSZ) & 63;
        float s = sc[c], h = sh[c];
        v.x = v.x * s + h; v.y = v.y * s + h; v.z = v.z * s + h; v.w = v.w * s + h;
        v.x = v.x / (1.f + __expf(-v.x));
        v.y = v.y / (1.f + __expf(-v.y));
        v.z = v.z / (1.f + __expf(-v.z));
        v.w = v.w / (1.f + __expf(-v.w));
        ((float4*)out)[i] = v;
    }
}

extern "C" void kernel_launch(void* const* d_in, const int* in_sizes, int n_in,
                              void* d_out, int out_size, void* d_ws, size_t ws_size,
                              hipStream_t stream) {
    const float* x   = (const float*)d_in[0];
    const float* Wk  = (const float*)d_in[1];
    const float* bk  = (const float*)d_in[2];
    const float* Wfc = (const float*)d_in[3];
    const float* gh  = (const float*)d_in[4];
    const float* bh  = (const float*)d_in[5];
    const float* Wf  = (const float*)d_in[6];
    const float* bf  = (const float*)d_in[7];
    const float* Wsm = (const float*)d_in[8];
    const float* bs  = (const float*)d_in[9];
    const float* Wc  = (const float*)d_in[10];
    const float* bc  = (const float*)d_in[11];
    const float* Ww  = (const float*)d_in[12];
    const float* bw  = (const float*)d_in[13];
    const float* go  = (const float*)d_in[14];
    const float* bo  = (const float*)d_in[15];
    float* out = (float*)d_out;
    float* ws  = (float*)d_ws;

    pool_kernel<<<dim3(1024), dim3(256), 0, stream>>>(x, ws);
    attn_kernel<<<dim3(1), dim3(256), 0, stream>>>(ws, Wfc, gh, bh, Wf, bf, Wsm, bs, Wc, bc, Ww, bw, bk);
    wprep_kernel<<<dim3(18, 16), dim3(256), 0, stream>>>(Wk, ws);
    conv_kernel<<<dim3(40, 16), dim3(512), 0, stream>>>(x, ws, out);
    bnstat_kernel<<<dim3(1), dim3(64), 0, stream>>>(ws, go, bo);
    bnact_kernel<<<dim3(2048), dim3(256), 0, stream>>>(out, ws);
}